// Round 1
// baseline (445.914 us; speedup 1.0000x reference)
//
#include <hip/hip_runtime.h>
#include <hip/hip_cooperative_groups.h>
#include <math.h>

namespace cg = cooperative_groups;

// Problem constants (B=1, C=256, W=64, N=4096, D=256)
#define N_TOK 4096
#define TSTRIDE 65  // LDS tile row stride (64 tokens + 1 pad)

// workspace layout (float offsets) — all atomics replaced by partial arrays
#define OFF_GU    0        // 1024  : g[c]*u[c] per modality
#define OFF_GUP   1024     // 32    : GU partials (4 modalities x 8 blocks)
#define OFF_BUP   1056     // 32    : BU partials
#define OFF_PM    1088     // 256   : per flash-block local max
#define OFF_PSE   1344     // 256   : per flash-block sum(exp)
#define OFF_PSR   1600     // 256   : per flash-block sum(exp*rinv*mu)
#define OFF_YB    1856     // 256   : yb = b_out + b_ff2 @ w_out
#define OFF_OUTP  2112     // 4096  : outv partials [16][256]
#define OFF_GGP   6208     // 8192  : geglu partials [32][256] (no bias)
#define OFF_YP    14400    // 4096  : y partials [16][256]
#define OFF_WS    18496    // 65536 : wsum partials [flash-block][c]
#define OFF_WC    84032    // 65536 : w_comb = w_ff2 @ w_out  [e][cout]
// total = 149568 floats = 598 KB

// Single cooperative kernel: 256 blocks x 256 threads, 5 grid syncs.
// Phases:
//   0: w_comb rows (all blocks) + q/u/gu (blocks 0..31) + yb (block 32)
//   B: flash pass over x/h/s/m (all 256 blocks, 1 per (modality, 64-token tile))
//   C: combine flash partials -> wfin -> outv partials (blocks 0..15)
//   D: LN(outv) + geglu matvec partials (blocks 0..31)
//   E: geglu activation + y partials via w_comb (blocks 0..15)
//   F: sum y partials, broadcast over spatial (all blocks, 1 channel each)
__global__ __launch_bounds__(256) void fused(
    const float* __restrict__ xg, const float* __restrict__ hg,
    const float* __restrict__ sg, const float* __restrict__ mg,
    const float* __restrict__ t, const float* __restrict__ wt,
    const float* __restrict__ bt,
    const float* __restrict__ wk0, const float* __restrict__ wk1,
    const float* __restrict__ wk2, const float* __restrict__ wk3,
    const float* __restrict__ wv0, const float* __restrict__ wv1,
    const float* __restrict__ wv2, const float* __restrict__ wv3,
    const float* __restrict__ g0, const float* __restrict__ g1,
    const float* __restrict__ g2, const float* __restrict__ g3,
    const float* __restrict__ be0, const float* __restrict__ be1,
    const float* __restrict__ be2, const float* __restrict__ be3,
    const float* __restrict__ w_geglu, const float* __restrict__ b_geglu,
    const float* __restrict__ w_ff2, const float* __restrict__ b_ff2,
    const float* __restrict__ g_res, const float* __restrict__ be_res,
    const float* __restrict__ w_out, const float* __restrict__ b_out,
    float* __restrict__ ws, float4* __restrict__ out4) {
  cg::grid_group grid = cg::this_grid();
  const int b = blockIdx.x;
  const int tid = threadIdx.x;

  __shared__ float tile[256 * TSTRIDE];  // 66560 B
  __shared__ float sA[256], sB[256], sC[256], sD[256], sE[256];
  __shared__ float sRed[16];

  // ---------------- Phase 0 ----------------
  // (a) every block: one w_comb row  e = b
  sA[tid] = w_ff2[b * 256 + tid];
  __syncthreads();
  {
    float acc = 0.f;
    #pragma unroll 8
    for (int d = 0; d < 256; ++d) acc += sA[d] * w_out[d * 256 + tid];
    ws[OFF_WC + b * 256 + tid] = acc;
  }
  if (b < 32) {
    // (b) q = t@wt + bt (redundant per block); u = wk@q rows -> gu, GU/BU
    const int mo = b >> 3;
    const int c0 = (b & 7) * 32;
    const float* wk = (mo == 0) ? wk0 : (mo == 1) ? wk1 : (mo == 2) ? wk2 : wk3;
    const float* g  = (mo == 0) ? g0  : (mo == 1) ? g1  : (mo == 2) ? g2  : g3;
    const float* be = (mo == 0) ? be0 : (mo == 1) ? be1 : (mo == 2) ? be2 : be3;

    float acc = bt[tid];
    #pragma unroll 8
    for (int c = 0; c < 256; ++c) acc += t[c] * wt[c * 256 + tid];
    sB[tid] = acc;  // q
    __syncthreads();

    const int w = tid >> 6, lane = tid & 63;
    const float4 qv = ((const float4*)sB)[lane];
    float lGU = 0.f, lBU = 0.f;
    #pragma unroll
    for (int r = 0; r < 8; ++r) {
      int c = c0 + w * 8 + r;
      float4 w4 = ((const float4*)(wk + c * 256))[lane];
      float sdot = w4.x * qv.x + w4.y * qv.y + w4.z * qv.z + w4.w * qv.w;
      for (int o = 32; o > 0; o >>= 1) sdot += __shfl_down(sdot, o, 64);
      if (lane == 0) {
        float u = sdot;
        float gu = g[c] * u;
        ws[OFF_GU + mo * 256 + c] = gu;
        lGU += gu;
        lBU += be[c] * u;
      }
    }
    __syncthreads();
    if (lane == 0) { sRed[w] = lGU; sRed[8 + w] = lBU; }
    __syncthreads();
    if (tid == 0) {
      ws[OFF_GUP + mo * 8 + (b & 7)] = sRed[0] + sRed[1] + sRed[2] + sRed[3];
      ws[OFF_BUP + mo * 8 + (b & 7)] = sRed[8] + sRed[9] + sRed[10] + sRed[11];
    }
  } else if (b == 32) {
    // (c) yb = b_out + b_ff2 @ w_out   (constant term of final projection)
    float acc = b_out[tid];
    #pragma unroll 8
    for (int d = 0; d < 256; ++d) acc += b_ff2[d] * w_out[d * 256 + tid];
    ws[OFF_YB + tid] = acc;
  }

  __threadfence();
  grid.sync();

  // ---------------- Phase B : flash pass ----------------
  {
    const int mo = b >> 6;
    const int jbase = (b & 63) * 64;
    const float* A = (mo == 0) ? xg : (mo == 1) ? hg : (mo == 2) ? sg : mg;

    sA[tid] = ws[OFF_GU + mo * 256 + tid];  // gu
    {
      const int cr = tid >> 4;   // row within group of 16
      const int jf = tid & 15;   // float4 index within row
      #pragma unroll 4
      for (int it = 0; it < 16; ++it) {
        int c = it * 16 + cr;
        float4 v4 = *(const float4*)(A + c * N_TOK + jbase + jf * 4);
        int base = c * TSTRIDE + jf * 4;
        tile[base] = v4.x; tile[base + 1] = v4.y;
        tile[base + 2] = v4.z; tile[base + 3] = v4.w;
      }
    }
    __syncthreads();

    // per-token stats: j = tid&63, quarter q = tid>>6
    {
      const int j = tid & 63, q = tid >> 6;
      float s1 = 0.f, s2 = 0.f, s3 = 0.f;
      #pragma unroll 8
      for (int i = 0; i < 64; ++i) {
        int c = q * 64 + i;
        float v = tile[c * TSTRIDE + j];
        s1 += v; s2 += v * v; s3 += v * sA[c];
      }
      sB[tid] = s1; sC[tid] = s2; sD[tid] = s3;
    }
    __syncthreads();
    if (tid < 64) {
      float S1 = sB[tid] + sB[tid + 64] + sB[tid + 128] + sB[tid + 192];
      float S2 = sC[tid] + sC[tid + 64] + sC[tid + 128] + sC[tid + 192];
      float S3 = sD[tid] + sD[tid + 64] + sD[tid + 128] + sD[tid + 192];
      float GU = 0.f, BU = 0.f;
      #pragma unroll
      for (int i = 0; i < 8; ++i) {
        GU += ws[OFF_GUP + mo * 8 + i];
        BU += ws[OFF_BUP + mo * 8 + i];
      }
      float mu = S1 * (1.0f / 256.0f);
      float var = S2 * (1.0f / 256.0f) - mu * mu;
      float rinv = rsqrtf(var + 1e-5f);
      sE[tid] = 0.0625f * (rinv * (S3 - mu * GU) + BU);  // simj
      sE[64 + tid] = rinv;
      sE[128 + tid] = mu;
    }
    __syncthreads();
    // local softmax partials over the 64 tokens (single wave, butterfly)
    if (tid < 64) {
      float sim = sE[tid];
      float mb_ = sim;
      #pragma unroll
      for (int o = 1; o < 64; o <<= 1) mb_ = fmaxf(mb_, __shfl_xor(mb_, o, 64));
      float e = expf(sim - mb_);
      float al = e * sE[64 + tid];
      sE[192 + tid] = al;  // alj
      float se = e, sr = al * sE[128 + tid];
      #pragma unroll
      for (int o = 1; o < 64; o <<= 1) {
        se += __shfl_xor(se, o, 64);
        sr += __shfl_xor(sr, o, 64);
      }
      if (tid == 0) {
        ws[OFF_PM + b] = mb_;
        ws[OFF_PSE + b] = se;
        ws[OFF_PSR + b] = sr;
      }
    }
    __syncthreads();
    // weighted channel sums: c = tid
    {
      float wsum = 0.f;
      #pragma unroll 8
      for (int j = 0; j < 64; ++j) wsum += sE[192 + j] * tile[tid * TSTRIDE + j];
      ws[OFF_WS + b * 256 + tid] = wsum;
    }
  }

  __threadfence();
  grid.sync();

  // ---------------- Phase C : combine flash partials ----------------
  if (b < 16) {
    const int mb = b >> 2;
    const int cbase = (b & 3) * 64;
    const float* wv = (mb == 0) ? wv0 : (mb == 1) ? wv1 : (mb == 2) ? wv2 : wv3;
    const float* g  = (mb == 0) ? g0  : (mb == 1) ? g1  : (mb == 2) ? g2  : g3;
    const float* be = (mb == 0) ? be0 : (mb == 1) ? be1 : (mb == 2) ? be2 : be3;

    sA[tid] = ws[OFF_PM + tid];   // pm
    sB[tid] = ws[OFF_PSE + tid];  // pse
    sC[tid] = ws[OFF_PSR + tid];  // psr
    __syncthreads();

    // M = global max
    float v = sA[tid];
    for (int o = 32; o > 0; o >>= 1) v = fmaxf(v, __shfl_down(v, o, 64));
    if ((tid & 63) == 0) sRed[tid >> 6] = v;
    __syncthreads();
    const float M = fmaxf(fmaxf(sRed[0], sRed[1]), fmaxf(sRed[2], sRed[3]));
    __syncthreads();

    const float f = expf(sA[tid] - M);
    const float fse = f * sB[tid];
    const bool mine = (tid >> 6) == mb;

    // S (all blocks)
    v = fse;
    for (int o = 32; o > 0; o >>= 1) v += __shfl_down(v, o, 64);
    if ((tid & 63) == 0) sRed[tid >> 6] = v;
    __syncthreads();
    if (tid == 0) sRed[8] = sRed[0] + sRed[1] + sRed[2] + sRed[3];  // sS
    __syncthreads();
    // A_m (this modality)
    v = mine ? fse : 0.f;
    for (int o = 32; o > 0; o >>= 1) v += __shfl_down(v, o, 64);
    if ((tid & 63) == 0) sRed[tid >> 6] = v;
    __syncthreads();
    if (tid == 0) sRed[9] = sRed[0] + sRed[1] + sRed[2] + sRed[3];  // sAm
    __syncthreads();
    // P_m (this modality)
    v = mine ? f * sC[tid] : 0.f;
    for (int o = 32; o > 0; o >>= 1) v += __shfl_down(v, o, 64);
    if ((tid & 63) == 0) sRed[tid >> 6] = v;
    __syncthreads();
    if (tid == 0) sRed[10] = sRed[0] + sRed[1] + sRed[2] + sRed[3];  // sPm
    if (tid < 64) sD[64 + tid] = expf(sA[mb * 64 + tid] - M);        // fsh
    __syncthreads();

    const float invS = 1.0f / sRed[8];

    // wfin chunk: thread (c_l = tid&63, bg = tid>>6) sums 16 flash blocks
    {
      const int c_l = tid & 63, bg = tid >> 6;
      float part = 0.f;
      #pragma unroll 4
      for (int i = 0; i < 16; ++i) {
        int fb = bg * 16 + i;
        part += sD[64 + fb] * ws[OFF_WS + (mb * 64 + fb) * 256 + cbase + c_l];
      }
      sB[tid] = part;  // scratch
    }
    __syncthreads();
    if (tid < 64) {
      float dot = (sB[tid] + sB[tid + 64] + sB[tid + 128] + sB[tid + 192]) * invS;
      int c = cbase + tid;
      sD[tid] = g[c] * (dot - sRed[10] * invS) + be[c] * (sRed[9] * invS);  // wfin
    }
    __syncthreads();

    // outv partial: d = tid over the 64-c chunk
    {
      float acc = 0.f;
      #pragma unroll 8
      for (int i = 0; i < 64; ++i) acc += sD[i] * wv[(cbase + i) * 256 + tid];
      ws[OFF_OUTP + b * 256 + tid] = acc;
    }
  }

  __threadfence();
  grid.sync();

  // ---------------- Phase D : LN(outv) + geglu partials ----------------
  if (b < 32) {
    float od = 0.f;
    #pragma unroll
    for (int i = 0; i < 16; ++i) od += ws[OFF_OUTP + i * 256 + tid];

    float v = od;
    for (int o = 32; o > 0; o >>= 1) v += __shfl_down(v, o, 64);
    if ((tid & 63) == 0) sRed[tid >> 6] = v;
    __syncthreads();
    float mu = (sRed[0] + sRed[1] + sRed[2] + sRed[3]) * (1.0f / 256.0f);
    __syncthreads();
    float dv = od - mu;
    v = dv * dv;
    for (int o = 32; o > 0; o >>= 1) v += __shfl_down(v, o, 64);
    if ((tid & 63) == 0) sRed[tid >> 6] = v;
    __syncthreads();
    float var = (sRed[0] + sRed[1] + sRed[2] + sRed[3]) * (1.0f / 256.0f);
    sA[tid] = dv * rsqrtf(var + 1e-5f) * g_res[tid] + be_res[tid];  // r
    __syncthreads();

    const int dt = b >> 4;
    const int d0 = (b & 15) * 16;
    float acc = 0.f;
    #pragma unroll
    for (int i = 0; i < 16; ++i) {
      int d = d0 + i;
      acc += sA[d] * w_geglu[d * 512 + dt * 256 + tid];
    }
    ws[OFF_GGP + b * 256 + tid] = acc;
  }

  __threadfence();
  grid.sync();

  // ---------------- Phase E : geglu activation + y partials ----------------
  if (b < 16) {
    const int e0 = b * 16;
    if (tid < 16) {
      float u = b_geglu[e0 + tid];
      float gate = b_geglu[256 + e0 + tid];
      #pragma unroll
      for (int p = 0; p < 16; ++p) {
        u    += ws[OFF_GGP + p * 256 + e0 + tid];
        gate += ws[OFF_GGP + (16 + p) * 256 + e0 + tid];
      }
      sA[tid] = u * 0.5f * gate * (1.0f + erff(gate * 0.70710678118654752f));
    }
    __syncthreads();
    float acc = 0.f;
    #pragma unroll
    for (int i = 0; i < 16; ++i) acc += sA[i] * ws[OFF_WC + (e0 + i) * 256 + tid];
    ws[OFF_YP + b * 256 + tid] = acc;
  }

  __threadfence();
  grid.sync();

  // ---------------- Phase F : finalize y + broadcast ----------------
  {
    float yv = ws[OFF_YB + tid];
    #pragma unroll
    for (int p = 0; p < 16; ++p) yv += ws[OFF_YP + p * 256 + tid];
    sA[tid] = yv;  // full y vector (channel = tid)
    __syncthreads();
    const float val = sA[b];  // block b owns channel b (4096 floats)
    const float4 v4 = make_float4(val, val, val, val);
    #pragma unroll
    for (int k = 0; k < 4; ++k) out4[b * 1024 + k * 256 + tid] = v4;
  }
}

// ---------------------------------------------------------------------------
extern "C" void kernel_launch(void* const* d_in, const int* in_sizes, int n_in,
                              void* d_out, int out_size, void* d_ws, size_t ws_size,
                              hipStream_t stream) {
  const float* x = (const float*)d_in[0];
  const float* h = (const float*)d_in[1];
  const float* s = (const float*)d_in[2];
  const float* m = (const float*)d_in[3];
  const float* t = (const float*)d_in[4];
  const float* wt = (const float*)d_in[5];
  const float* bt = (const float*)d_in[6];
  const float* wk_x = (const float*)d_in[7];
  const float* wv_x = (const float*)d_in[8];
  const float* g_x = (const float*)d_in[9];
  const float* be_x = (const float*)d_in[10];
  const float* wk_h = (const float*)d_in[11];
  const float* wv_h = (const float*)d_in[12];
  const float* g_h = (const float*)d_in[13];
  const float* be_h = (const float*)d_in[14];
  const float* wk_s = (const float*)d_in[15];
  const float* wv_s = (const float*)d_in[16];
  const float* g_s = (const float*)d_in[17];
  const float* be_s = (const float*)d_in[18];
  const float* wk_m = (const float*)d_in[19];
  const float* wv_m = (const float*)d_in[20];
  const float* g_m = (const float*)d_in[21];
  const float* be_m = (const float*)d_in[22];
  const float* w_geglu = (const float*)d_in[23];
  const float* b_geglu = (const float*)d_in[24];
  const float* w_ff2 = (const float*)d_in[25];
  const float* b_ff2 = (const float*)d_in[26];
  const float* g_res = (const float*)d_in[27];
  const float* be_res = (const float*)d_in[28];
  const float* w_out = (const float*)d_in[29];
  const float* b_out = (const float*)d_in[30];
  float* ws = (float*)d_ws;
  float4* out4 = (float4*)d_out;

  void* args[] = {
      (void*)&x, (void*)&h, (void*)&s, (void*)&m,
      (void*)&t, (void*)&wt, (void*)&bt,
      (void*)&wk_x, (void*)&wk_h, (void*)&wk_s, (void*)&wk_m,
      (void*)&wv_x, (void*)&wv_h, (void*)&wv_s, (void*)&wv_m,
      (void*)&g_x, (void*)&g_h, (void*)&g_s, (void*)&g_m,
      (void*)&be_x, (void*)&be_h, (void*)&be_s, (void*)&be_m,
      (void*)&w_geglu, (void*)&b_geglu, (void*)&w_ff2, (void*)&b_ff2,
      (void*)&g_res, (void*)&be_res, (void*)&w_out, (void*)&b_out,
      (void*)&ws, (void*)&out4};

  hipLaunchCooperativeKernel((const void*)fused, dim3(256), dim3(256), args, 0,
                             stream);
}

// Round 2
// 163.293 us; speedup vs baseline: 2.7308x; 2.7308x over previous
//
#include <hip/hip_runtime.h>
#include <math.h>

// Problem constants (B=1, C=256, W=64, N=4096, D=256)
#define N_TOK 4096

// workspace layout (float offsets)
#define OFF_GU    0        // 1024  : g[c]*u[c] per modality
#define OFF_GUP   1024     // 32    : GU partials (4 modalities x 8 blocks)
#define OFF_BUP   1056     // 32    : BU partials
#define OFF_PM    1088     // 256   : per flash-block local max
#define OFF_PSE   1344     // 256   : per flash-block sum(exp)
#define OFF_PSR   1600     // 256   : per flash-block sum(exp*rinv*mu)
#define OFF_OUTV  1856     // 256   : attention output vector (atomic, init 0)
#define OFF_GG    2112     // 512   : geglu pre-activation (atomic, init b_geglu)
#define OFF_Y     2624     // 256   : final channel vector (atomic, init b_out)
#define OFF_WS    3072     // 65536 : wsum partials [flash-block][c]
#define OFF_WC    69632    // 65536 : w_comb = w_ff2 @ w_out  [e][cout]

#define TSTRIDE 65         // LDS tile row stride (64 tokens + 1 pad -> 2-way max)

// ---------------------------------------------------------------------------
// K0: grid 289.
//   blocks 0..255  : w_comb row e = w_ff2[e,:] @ w_out            (row per block)
//   blocks 256..287: q = t@wt+bt (redundant) -> u = wk@q rows -> gu, GU/BU
//   block 288      : init atomic accumulators (outv=0, gg=b_geglu, y=b_out)
__global__ __launch_bounds__(256) void k0(
    const float* __restrict__ t, const float* __restrict__ wt,
    const float* __restrict__ bt,
    const float* __restrict__ wk0, const float* __restrict__ wk1,
    const float* __restrict__ wk2, const float* __restrict__ wk3,
    const float* __restrict__ g0, const float* __restrict__ g1,
    const float* __restrict__ g2, const float* __restrict__ g3,
    const float* __restrict__ be0, const float* __restrict__ be1,
    const float* __restrict__ be2, const float* __restrict__ be3,
    const float* __restrict__ w_ff2, const float* __restrict__ w_out,
    const float* __restrict__ b_geglu, const float* __restrict__ b_ff2,
    const float* __restrict__ b_out, float* __restrict__ ws) {
  const int gid = blockIdx.x;
  const int tid = threadIdx.x;
  __shared__ float sh[264];

  if (gid < 256) {
    // w_comb[e=gid][cout=tid] = sum_d w_ff2[e,d] * w_out[d,cout]
    sh[tid] = w_ff2[gid * 256 + tid];
    __syncthreads();
    float acc = 0.f;
    #pragma unroll 8
    for (int d = 0; d < 256; ++d) acc += sh[d] * w_out[d * 256 + tid];
    ws[OFF_WC + gid * 256 + tid] = acc;
  } else if (gid < 288) {
    const int local = gid - 256;
    const int m = local >> 3;
    const int c0 = (local & 7) * 32;
    const float* wk = (m == 0) ? wk0 : (m == 1) ? wk1 : (m == 2) ? wk2 : wk3;
    const float* g  = (m == 0) ? g0  : (m == 1) ? g1  : (m == 2) ? g2  : g3;
    const float* be = (m == 0) ? be0 : (m == 1) ? be1 : (m == 2) ? be2 : be3;

    float acc = bt[tid];
    #pragma unroll 8
    for (int c = 0; c < 256; ++c) acc += t[c] * wt[c * 256 + tid];
    sh[tid] = acc;               // q
    __syncthreads();

    const int w = tid >> 6, lane = tid & 63;
    const float4 qv = ((const float4*)sh)[lane];
    float lGU = 0.f, lBU = 0.f;
    #pragma unroll
    for (int r = 0; r < 8; ++r) {
      int c = c0 + w * 8 + r;
      float4 w4 = ((const float4*)(wk + c * 256))[lane];
      float sdot = w4.x * qv.x + w4.y * qv.y + w4.z * qv.z + w4.w * qv.w;
      for (int o = 32; o > 0; o >>= 1) sdot += __shfl_down(sdot, o, 64);
      if (lane == 0) {
        float u = sdot;
        float gu = g[c] * u;
        ws[OFF_GU + m * 256 + c] = gu;
        lGU += gu;
        lBU += be[c] * u;
      }
    }
    __syncthreads();
    if (lane == 0) { sh[256 + w] = lGU; sh[260 + w] = lBU; }
    __syncthreads();
    if (tid == 0) {
      ws[OFF_GUP + m * 8 + (local & 7)] = sh[256] + sh[257] + sh[258] + sh[259];
      ws[OFF_BUP + m * 8 + (local & 7)] = sh[260] + sh[261] + sh[262] + sh[263];
    }
  } else {
    ws[OFF_OUTV + tid] = 0.0f;
    ws[OFF_GG + tid] = b_geglu[tid];
    ws[OFF_GG + 256 + tid] = b_geglu[256 + tid];
    ws[OFF_Y + tid] = b_out[tid];
  }
}

// ---------------------------------------------------------------------------
// K2: flash-style single pass. grid 256 (64 blocks/modality, 64 tokens each).
// Stage tile[c][j] (stride-65) in LDS; per-token stats -> sim/mu/rinv;
// local softmax over 64 tokens; weighted channel sums wsum[c].
__global__ __launch_bounds__(256) void k2(
    const float* __restrict__ A0, const float* __restrict__ A1,
    const float* __restrict__ A2, const float* __restrict__ A3,
    float* __restrict__ ws) {
  const int b = blockIdx.x;
  const int m = b >> 6;
  const int jbase = (b & 63) * 64;
  const int tid = threadIdx.x;
  const float* A = (m == 0) ? A0 : (m == 1) ? A1 : (m == 2) ? A2 : A3;

  __shared__ float tile[256 * TSTRIDE];  // 66560 B
  __shared__ float gu_sh[256];
  __shared__ float r1[256], r2[256], r3[256];
  __shared__ float simj[64], rinvj[64], muj[64], alj[64];

  gu_sh[tid] = ws[OFF_GU + m * 256 + tid];

  // load tile: 16 iters, 16 rows x 16 float4 per iter
  {
    const int cr = tid >> 4;      // row within group of 16
    const int jf = tid & 15;      // float4 index within row
    #pragma unroll 4
    for (int it = 0; it < 16; ++it) {
      int c = it * 16 + cr;
      float4 v = *(const float4*)(A + c * N_TOK + jbase + jf * 4);
      int base = c * TSTRIDE + jf * 4;
      tile[base] = v.x; tile[base + 1] = v.y;
      tile[base + 2] = v.z; tile[base + 3] = v.w;
    }
  }
  __syncthreads();

  // per-token stats: j = tid&63, quarter q = tid>>6
  {
    const int j = tid & 63, q = tid >> 6;
    float s1 = 0.f, s2 = 0.f, s3 = 0.f;
    #pragma unroll 8
    for (int i = 0; i < 64; ++i) {
      int c = q * 64 + i;
      float v = tile[c * TSTRIDE + j];
      s1 += v; s2 += v * v; s3 += v * gu_sh[c];
    }
    r1[tid] = s1; r2[tid] = s2; r3[tid] = s3;
  }
  __syncthreads();
  if (tid < 64) {
    float S1 = r1[tid] + r1[tid + 64] + r1[tid + 128] + r1[tid + 192];
    float S2 = r2[tid] + r2[tid + 64] + r2[tid + 128] + r2[tid + 192];
    float S3 = r3[tid] + r3[tid + 64] + r3[tid + 128] + r3[tid + 192];
    float GU = 0.f, BU = 0.f;
    #pragma unroll
    for (int i = 0; i < 8; ++i) {
      GU += ws[OFF_GUP + m * 8 + i];
      BU += ws[OFF_BUP + m * 8 + i];
    }
    float mu = S1 * (1.0f / 256.0f);
    float var = S2 * (1.0f / 256.0f) - mu * mu;
    float rinv = rsqrtf(var + 1e-5f);
    simj[tid] = 0.0625f * (rinv * (S3 - mu * GU) + BU);
    muj[tid] = mu;
    rinvj[tid] = rinv;
  }
  __syncthreads();
  // local softmax partials over the 64 tokens (single wave, butterfly)
  if (tid < 64) {
    float sim = simj[tid];
    float mb = sim;
    #pragma unroll
    for (int o = 1; o < 64; o <<= 1) mb = fmaxf(mb, __shfl_xor(mb, o, 64));
    float e = expf(sim - mb);
    float al = e * rinvj[tid];
    alj[tid] = al;
    float se = e, sr = al * muj[tid];
    #pragma unroll
    for (int o = 1; o < 64; o <<= 1) {
      se += __shfl_xor(se, o, 64);
      sr += __shfl_xor(sr, o, 64);
    }
    if (tid == 0) {
      ws[OFF_PM + b] = mb;
      ws[OFF_PSE + b] = se;
      ws[OFF_PSR + b] = sr;
    }
  }
  __syncthreads();
  // weighted channel sums: c = tid
  {
    float wsum = 0.f;
    #pragma unroll 8
    for (int j = 0; j < 64; ++j) wsum += alj[j] * tile[tid * TSTRIDE + j];
    ws[OFF_WS + b * 256 + tid] = wsum;
  }
}

// ---------------------------------------------------------------------------
// K3: combine flash partials -> wfin chunk -> outv matvec partial.
// grid 16: mb = b>>2, cbase = (b&3)*64.
__global__ __launch_bounds__(256) void k3(
    const float* __restrict__ wv0, const float* __restrict__ wv1,
    const float* __restrict__ wv2, const float* __restrict__ wv3,
    const float* __restrict__ g0, const float* __restrict__ g1,
    const float* __restrict__ g2, const float* __restrict__ g3,
    const float* __restrict__ be0, const float* __restrict__ be1,
    const float* __restrict__ be2, const float* __restrict__ be3,
    float* __restrict__ ws) {
  const int b = blockIdx.x;
  const int mb = b >> 2;
  const int cbase = (b & 3) * 64;
  const int tid = threadIdx.x;
  const float* wv = (mb == 0) ? wv0 : (mb == 1) ? wv1 : (mb == 2) ? wv2 : wv3;
  const float* g  = (mb == 0) ? g0  : (mb == 1) ? g1  : (mb == 2) ? g2  : g3;
  const float* be = (mb == 0) ? be0 : (mb == 1) ? be1 : (mb == 2) ? be2 : be3;

  __shared__ float pm[256], pse[256], psr[256];
  __shared__ float red[4];
  __shared__ float wfin[64], fsh[64];
  __shared__ float sS, sAm, sPm;

  pm[tid] = ws[OFF_PM + tid];
  pse[tid] = ws[OFF_PSE + tid];
  psr[tid] = ws[OFF_PSR + tid];
  __syncthreads();

  // M = global max
  float v = pm[tid];
  for (int o = 32; o > 0; o >>= 1) v = fmaxf(v, __shfl_down(v, o, 64));
  if ((tid & 63) == 0) red[tid >> 6] = v;
  __syncthreads();
  const float M = fmaxf(fmaxf(red[0], red[1]), fmaxf(red[2], red[3]));
  __syncthreads();

  const float f = expf(pm[tid] - M);
  const float fse = f * pse[tid];
  const bool mine = (tid >> 6) == mb;

  // S (all blocks)
  v = fse;
  for (int o = 32; o > 0; o >>= 1) v += __shfl_down(v, o, 64);
  if ((tid & 63) == 0) red[tid >> 6] = v;
  __syncthreads();
  if (tid == 0) sS = red[0] + red[1] + red[2] + red[3];
  __syncthreads();
  // A_m (this modality)
  v = mine ? fse : 0.f;
  for (int o = 32; o > 0; o >>= 1) v += __shfl_down(v, o, 64);
  if ((tid & 63) == 0) red[tid >> 6] = v;
  __syncthreads();
  if (tid == 0) sAm = red[0] + red[1] + red[2] + red[3];
  __syncthreads();
  // P_m (this modality)
  v = mine ? f * psr[tid] : 0.f;
  for (int o = 32; o > 0; o >>= 1) v += __shfl_down(v, o, 64);
  if ((tid & 63) == 0) red[tid >> 6] = v;
  __syncthreads();
  if (tid == 0) sPm = red[0] + red[1] + red[2] + red[3];
  if (tid < 64) fsh[tid] = expf(pm[mb * 64 + tid] - M);
  __syncthreads();

  const float invS = 1.0f / sS;

  // wfin chunk: thread (c_l = tid&63, bg = tid>>6) sums 16 flash blocks
  {
    const int c_l = tid & 63, bg = tid >> 6;
    float part = 0.f;
    #pragma unroll 4
    for (int i = 0; i < 16; ++i) {
      int fb = bg * 16 + i;                  // block within modality
      part += fsh[fb] * ws[OFF_WS + (mb * 64 + fb) * 256 + cbase + c_l];
    }
    pse[tid] = part;                         // reuse as scratch
  }
  __syncthreads();
  if (tid < 64) {
    float dot = (pse[tid] + pse[tid + 64] + pse[tid + 128] + pse[tid + 192]) * invS;
    int c = cbase + tid;
    wfin[tid] = g[c] * (dot - sPm * invS) + be[c] * (sAm * invS);
  }
  __syncthreads();

  // outv partial: d = tid over the 64-c chunk
  {
    float acc = 0.f;
    #pragma unroll 8
    for (int i = 0; i < 64; ++i) acc += wfin[i] * wv[(cbase + i) * 256 + tid];
    atomicAdd(&ws[OFF_OUTV + tid], acc);
  }
}

// ---------------------------------------------------------------------------
// K4: LN (redundant per block) + geglu matvec partial. grid 32.
__global__ __launch_bounds__(256) void k4(
    const float* __restrict__ g_res, const float* __restrict__ be_res,
    const float* __restrict__ w_geglu, float* __restrict__ ws) {
  const int gid = blockIdx.x;
  const int tid = threadIdx.x;
  __shared__ float r_sh[256];
  __shared__ float red[4];

  float od = ws[OFF_OUTV + tid];
  float v = od;
  for (int o = 32; o > 0; o >>= 1) v += __shfl_down(v, o, 64);
  if ((tid & 63) == 0) red[tid >> 6] = v;
  __syncthreads();
  float mu = (red[0] + red[1] + red[2] + red[3]) * (1.0f / 256.0f);
  __syncthreads();
  float dv = od - mu;
  v = dv * dv;
  for (int o = 32; o > 0; o >>= 1) v += __shfl_down(v, o, 64);
  if ((tid & 63) == 0) red[tid >> 6] = v;
  __syncthreads();
  float var = (red[0] + red[1] + red[2] + red[3]) * (1.0f / 256.0f);
  r_sh[tid] = dv * rsqrtf(var + 1e-5f) * g_res[tid] + be_res[tid];
  __syncthreads();

  const int dt = gid >> 4;
  const int d0 = (gid & 15) * 16;
  float acc = 0.f;
  #pragma unroll
  for (int i = 0; i < 16; ++i) {
    int d = d0 + i;
    acc += r_sh[d] * w_geglu[d * 512 + dt * 256 + tid];
  }
  atomicAdd(&ws[OFF_GG + dt * 256 + tid], acc);
}

// ---------------------------------------------------------------------------
// K5: grid 32. blocks 0..15: y += geglu(gg)-chunk @ w_comb;
//     blocks 16..31: y += b_ff2-chunk @ w_out.
__global__ __launch_bounds__(256) void k5(
    const float* __restrict__ b_ff2, const float* __restrict__ w_out,
    float* __restrict__ ws) {
  const int gid = blockIdx.x;
  const int tid = threadIdx.x;
  float acc = 0.f;
  if (gid < 16) {
    const int e0 = gid * 16;
    #pragma unroll
    for (int i = 0; i < 16; ++i) {
      int e = e0 + i;
      float u = ws[OFF_GG + e];
      float gate = ws[OFF_GG + 256 + e];
      float ffin = u * 0.5f * gate * (1.0f + erff(gate * 0.70710678118654752f));
      acc += ffin * ws[OFF_WC + e * 256 + tid];
    }
  } else {
    const int d0 = (gid - 16) * 16;
    #pragma unroll
    for (int i = 0; i < 16; ++i) {
      int d = d0 + i;
      acc += b_ff2[d] * w_out[d * 256 + tid];
    }
  }
  atomicAdd(&ws[OFF_Y + tid], acc);
}

// ---------------------------------------------------------------------------
// K6: broadcast y over spatial positions. grid 512, 2 float4 each.
__global__ __launch_bounds__(256) void k6(const float* __restrict__ ws,
                                          float4* __restrict__ out4) {
  const int gid = blockIdx.x;
  const int tid = threadIdx.x;
  #pragma unroll
  for (int k = 0; k < 2; ++k) {
    const int idx = gid * 512 + k * 256 + tid;  // 0..262143
    const int c = idx >> 10;
    float v = ws[OFF_Y + c];
    out4[idx] = make_float4(v, v, v, v);
  }
}

// ---------------------------------------------------------------------------
extern "C" void kernel_launch(void* const* d_in, const int* in_sizes, int n_in,
                              void* d_out, int out_size, void* d_ws, size_t ws_size,
                              hipStream_t stream) {
  const float* x = (const float*)d_in[0];
  const float* h = (const float*)d_in[1];
  const float* s = (const float*)d_in[2];
  const float* m = (const float*)d_in[3];
  const float* t = (const float*)d_in[4];
  const float* wt = (const float*)d_in[5];
  const float* bt = (const float*)d_in[6];
  const float* wk_x = (const float*)d_in[7];
  const float* wv_x = (const float*)d_in[8];
  const float* g_x = (const float*)d_in[9];
  const float* be_x = (const float*)d_in[10];
  const float* wk_h = (const float*)d_in[11];
  const float* wv_h = (const float*)d_in[12];
  const float* g_h = (const float*)d_in[13];
  const float* be_h = (const float*)d_in[14];
  const float* wk_s = (const float*)d_in[15];
  const float* wv_s = (const float*)d_in[16];
  const float* g_s = (const float*)d_in[17];
  const float* be_s = (const float*)d_in[18];
  const float* wk_m = (const float*)d_in[19];
  const float* wv_m = (const float*)d_in[20];
  const float* g_m = (const float*)d_in[21];
  const float* be_m = (const float*)d_in[22];
  const float* w_geglu = (const float*)d_in[23];
  const float* b_geglu = (const float*)d_in[24];
  const float* w_ff2 = (const float*)d_in[25];
  const float* b_ff2 = (const float*)d_in[26];
  const float* g_res = (const float*)d_in[27];
  const float* be_res = (const float*)d_in[28];
  const float* w_out = (const float*)d_in[29];
  const float* b_out = (const float*)d_in[30];
  float* ws = (float*)d_ws;

  k0<<<dim3(289), dim3(256), 0, stream>>>(t, wt, bt,
      wk_x, wk_h, wk_s, wk_m, g_x, g_h, g_s, g_m, be_x, be_h, be_s, be_m,
      w_ff2, w_out, b_geglu, b_ff2, b_out, ws);
  k2<<<dim3(256), dim3(256), 0, stream>>>(x, h, s, m, ws);
  k3<<<dim3(16), dim3(256), 0, stream>>>(wv_x, wv_h, wv_s, wv_m,
      g_x, g_h, g_s, g_m, be_x, be_h, be_s, be_m, ws);
  k4<<<dim3(32), dim3(256), 0, stream>>>(g_res, be_res, w_geglu, ws);
  k5<<<dim3(32), dim3(256), 0, stream>>>(b_ff2, w_out, ws);
  k6<<<dim3(512), dim3(256), 0, stream>>>(ws, (float4*)d_out);
}